// Round 6
// baseline (357.423 us; speedup 1.0000x reference)
//
#include <hip/hip_runtime.h>

#define PP   20000
#define NN   16
#define DD   128
#define HH   8
#define ANC  5
#define FF   512
#define PD   640
#define ROWS (PP * ANC)          // 100000 rows of [128]
#define KSTRIDE 648              // shorts; LDS K rows: 16B-aligned, banks spread
#define SEG  20480               // shorts per d_out segment (80 rows x 128 x 2 halves)

// d_out overlay (per 80-row segment s, byte base s*40960):
//   [0,20480)B  : bf16 x rows   (row r -> s=r/80, local=r%80, +local*256B)
//   [20480,40960)B : bf16 t2 rows (same row mapping)
// k_ffn block s reads exactly segment s and finally overwrites it with fp32 out.

typedef __attribute__((ext_vector_type(8))) short  bf8;     // 8 bf16 (4 VGPRs)
typedef __attribute__((ext_vector_type(8))) unsigned short ushort8;
typedef __attribute__((ext_vector_type(4))) unsigned short us4;
typedef __attribute__((ext_vector_type(4))) float  f32x4;

__device__ inline float bf2f(unsigned short u) {
  union { unsigned int i; float f; } v; v.i = ((unsigned int)u) << 16; return v.f;
}
__device__ inline unsigned short f2bf(float f) {
  union { float f; unsigned int i; } v; v.f = f;
  unsigned int r = v.i + 0x7FFFu + ((v.i >> 16) & 1u);
  return (unsigned short)(r >> 16);
}

// ---------------------------------------------------------------------------
// K0: weight conversion fp32 -> bf16 (once per launch)
// ---------------------------------------------------------------------------
__global__ void k_wconv(const float* __restrict__ Wo, const float* __restrict__ W1,
                        const float* __restrict__ W2, const float* __restrict__ Wq,
                        const float* __restrict__ Wk,
                        unsigned short* __restrict__ Wob, unsigned short* __restrict__ W1b,
                        unsigned short* __restrict__ W2b, unsigned short* __restrict__ Wqb,
                        unsigned short* __restrict__ Wkb)
{
  int i = blockIdx.x * 256 + threadIdx.x;
  if (i < 16384) { Wob[i] = f2bf(Wo[i]); Wqb[i] = f2bf(Wq[i]); Wkb[i] = f2bf(Wk[i]); }
  if (i < 65536) { W1b[i] = f2bf(W1[i]); W2b[i] = f2bf(W2[i]); }
}

// ---------------------------------------------------------------------------
// K1a: transpose tgt [p][e*5+a] -> bf16 x rows [p*5+a][e] into d_out overlay.
// ---------------------------------------------------------------------------
__global__ __launch_bounds__(320) void k_xpose(
    const float* __restrict__ tgt, unsigned short* __restrict__ xb)
{
  __shared__ float xs[5 * 1032];
  const int t = threadIdx.x;
  const int p0 = blockIdx.x * 8;
  const float* src = tgt + (size_t)p0 * PD;
#pragma unroll
  for (int i = 0; i < 16; ++i) {
    int lin = t + i * 320;
    float v = src[lin];
    int pt = lin / PD;
    int rem = lin - pt * PD;
    int e = rem / 5;
    int a = rem - e * 5;
    xs[a * 1032 + e * 8 + pt] = v;
  }
  __syncthreads();
  // 40 rows per block; rows r0..r0+39 live in segment r0/80, half (blockIdx&1)
  const size_t base = (size_t)(blockIdx.x >> 1) * SEG + (size_t)(blockIdx.x & 1) * 5120;
  for (int i = t; i < 5120; i += 320) {
    int row_l = i >> 7, col = i & 127;
    int pt = row_l / 5, a = row_l - pt * 5;
    xb[base + i] = f2bf(xs[a * 1032 + col * 8 + pt]);
  }
}

// ---------------------------------------------------------------------------
// K1b: MFMA GEMM q = x@Wq^T, k = x@Wk^T; writes combined kq rows:
// kqb[p][0..640) = k (layout e*5+a), kqb[p][640..1280) = q.
// ---------------------------------------------------------------------------
__global__ __launch_bounds__(256) void k_qk_gemm(
    const unsigned short* __restrict__ xb, const unsigned short* __restrict__ Wqb,
    const unsigned short* __restrict__ Wkb, unsigned short* __restrict__ kqb)
{
  __shared__ unsigned short Sb[80 * 136];
  const int t = threadIdx.x;
  const int w = t >> 6, l = t & 63;
  const int lc = l & 15, kg = l >> 4;
  const int p0 = blockIdx.x * 16;
  const unsigned short* xseg = xb + (size_t)blockIdx.x * SEG;  // 80 rows x 128

  f32x4 zq[5][2], zk[5][2];
#pragma unroll
  for (int m = 0; m < 5; ++m)
#pragma unroll
    for (int n = 0; n < 2; ++n) {
      zq[m][n] = (f32x4){0.f, 0.f, 0.f, 0.f};
      zk[m][n] = (f32x4){0.f, 0.f, 0.f, 0.f};
    }
  bf8 wq[2][4], wk[2][4];
#pragma unroll
  for (int nt = 0; nt < 2; ++nt)
#pragma unroll
    for (int kf = 0; kf < 4; ++kf) {
      size_t wo = (size_t)((2 * w + nt) * 16 + lc) * DD + kf * 32 + kg * 8;
      wq[nt][kf] = *reinterpret_cast<const bf8*>(&Wqb[wo]);
      wk[nt][kf] = *reinterpret_cast<const bf8*>(&Wkb[wo]);
    }
#pragma unroll
  for (int mt = 0; mt < 5; ++mt) {
    const unsigned short* ap = xseg + (mt * 16 + lc) * DD + kg * 8;
    bf8 a0 = *reinterpret_cast<const bf8*>(ap);
    bf8 a1 = *reinterpret_cast<const bf8*>(ap + 32);
    bf8 a2 = *reinterpret_cast<const bf8*>(ap + 64);
    bf8 a3 = *reinterpret_cast<const bf8*>(ap + 96);
#pragma unroll
    for (int nt = 0; nt < 2; ++nt) {
      zq[mt][nt] = __builtin_amdgcn_mfma_f32_16x16x32_bf16(a0, wq[nt][0], zq[mt][nt], 0, 0, 0);
      zq[mt][nt] = __builtin_amdgcn_mfma_f32_16x16x32_bf16(a1, wq[nt][1], zq[mt][nt], 0, 0, 0);
      zq[mt][nt] = __builtin_amdgcn_mfma_f32_16x16x32_bf16(a2, wq[nt][2], zq[mt][nt], 0, 0, 0);
      zq[mt][nt] = __builtin_amdgcn_mfma_f32_16x16x32_bf16(a3, wq[nt][3], zq[mt][nt], 0, 0, 0);
      zk[mt][nt] = __builtin_amdgcn_mfma_f32_16x16x32_bf16(a0, wk[nt][0], zk[mt][nt], 0, 0, 0);
      zk[mt][nt] = __builtin_amdgcn_mfma_f32_16x16x32_bf16(a1, wk[nt][1], zk[mt][nt], 0, 0, 0);
      zk[mt][nt] = __builtin_amdgcn_mfma_f32_16x16x32_bf16(a2, wk[nt][2], zk[mt][nt], 0, 0, 0);
      zk[mt][nt] = __builtin_amdgcn_mfma_f32_16x16x32_bf16(a3, wk[nt][3], zk[mt][nt], 0, 0, 0);
    }
  }
  // ---- epilogue: Q half (offset 640), then K half (offset 0) via LDS ----
#pragma unroll
  for (int mt = 0; mt < 5; ++mt)
#pragma unroll
    for (int j = 0; j < 4; ++j)
#pragma unroll
      for (int nt = 0; nt < 2; ++nt)
        Sb[(mt * 16 + kg * 4 + j) * 136 + (2 * w + nt) * 16 + lc] = f2bf(zq[mt][nt][j]);
  __syncthreads();
  for (int i = t; i < 10240; i += 256) {
    int pl = i / 640, rem = i - pl * 640;
    int d = rem / 5, a = rem - d * 5;
    kqb[(size_t)(p0 + pl) * 1280 + 640 + rem] = Sb[(pl * 5 + a) * 136 + d];
  }
  __syncthreads();
#pragma unroll
  for (int mt = 0; mt < 5; ++mt)
#pragma unroll
    for (int j = 0; j < 4; ++j)
#pragma unroll
      for (int nt = 0; nt < 2; ++nt)
        Sb[(mt * 16 + kg * 4 + j) * 136 + (2 * w + nt) * 16 + lc] = f2bf(zk[mt][nt][j]);
  __syncthreads();
  for (int i = t; i < 10240; i += 256) {
    int pl = i / 640, rem = i - pl * 640;
    int d = rem / 5, a = rem - d * 5;
    kqb[(size_t)(p0 + pl) * 1280 + rem] = Sb[(pl * 5 + a) * 136 + d];
  }
}

// ---------------------------------------------------------------------------
// K2: attention. One point per block. K gathered to bf16 LDS; V loads pinned
// in registers via asm keep-alive (issued before the gather barrier, consumed
// in PV — latency hidden under gather+dot). 5 blocks/CU.
// ---------------------------------------------------------------------------
__global__ __launch_bounds__(256, 5) void k_attn(
    const unsigned short* __restrict__ kqb, const int* __restrict__ idx,
    const float* __restrict__ dist, unsigned short* __restrict__ t2b)
{
  __shared__ unsigned short ksh[NN * KSTRIDE];
  __shared__ unsigned short qsh[648];
  __shared__ float sc[128];
  __shared__ float att[128];
  __shared__ int sidx[NN];
  const int t = threadIdx.x;
  const int p = blockIdx.x;
  if (t < NN) sidx[t] = idx[p * NN + t];
  if (t < 80)
    *reinterpret_cast<ushort8*>(&qsh[t * 8]) =
        *reinterpret_cast<const ushort8*>(&kqb[(size_t)p * 1280 + 640 + t * 8]);
  float dv = 0.f;
  if (t < 128) dv = dist[(size_t)p * 128 + (t & 15) * 8 + (t >> 4)];
  __syncthreads();
  // V preload into registers; pinned below so latency hides under gather + dot
  uint2 vbits[16];
  const int o0 = (t < 160) ? t * 4 : 0;
  if (t < 160) {
#pragma unroll
    for (int n = 0; n < 16; ++n)
      vbits[n] = *reinterpret_cast<const uint2*>(&kqb[(size_t)sidx[n] * 1280 + 640 + o0]);
  }
  // gather K halves -> LDS (raw bf16, b128 writes)
#pragma unroll
  for (int it = 0; it < 5; ++it) {
    int u = t + it * 256;
    int n = u / 80, c = u - n * 80;
    *reinterpret_cast<ushort8*>(&ksh[n * KSTRIDE + c * 8]) =
        *reinterpret_cast<const ushort8*>(&kqb[(size_t)sidx[n] * 1280 + c * 8]);
  }
  // Pin V in VGPRs: compiler must materialize loads here (wait overlaps the
  // barrier below) and cannot re-load them in the PV phase.
  if (t < 160) {
#pragma unroll
    for (int n = 0; n < 16; ++n)
      asm volatile("" : "+v"(vbits[n].x), "+v"(vbits[n].y));
  }
  __syncthreads();
  if (t < 128) {
    int n = t & 15, h = t >> 4;
    const unsigned short* kp = &ksh[n * KSTRIDE + h * 80];
    const unsigned short* qp = &qsh[h * 80];
    float acc = 0.f;
#pragma unroll
    for (int j = 0; j < 10; ++j) {
      ushort8 kv8 = *reinterpret_cast<const ushort8*>(&kp[j * 8]);
      ushort8 qv8 = *reinterpret_cast<const ushort8*>(&qp[j * 8]);
#pragma unroll
      for (int jj = 0; jj < 8; ++jj) acc += bf2f(kv8[jj]) * bf2f(qv8[jj]);
    }
    sc[h * 16 + n] = (acc + dv) * 0.25f;
  }
  __syncthreads();
  if (t < 8) {
    float m = -1e30f;
#pragma unroll
    for (int n = 0; n < 16; ++n) m = fmaxf(m, sc[t * 16 + n]);
    float s = 0.f;
    float ev[16];
#pragma unroll
    for (int n = 0; n < 16; ++n) { ev[n] = __expf(sc[t * 16 + n] - m); s += ev[n]; }
    float inv = 1.f / s;
#pragma unroll
    for (int n = 0; n < 16; ++n) att[t * 16 + n] = ev[n] * inv;
  }
  __syncthreads();
  if (t < 160) {
    const int h = o0 / 80;     // 4-elem chunk never straddles a head (4 | 80)
    float facc[4] = {0.f, 0.f, 0.f, 0.f};
#pragma unroll
    for (int n = 0; n < 16; ++n) {
      float aw = att[h * 16 + n];
      facc[0] += aw * bf2f((unsigned short)(vbits[n].x & 0xffffu));
      facc[1] += aw * bf2f((unsigned short)(vbits[n].x >> 16));
      facc[2] += aw * bf2f((unsigned short)(vbits[n].y & 0xffffu));
      facc[3] += aw * bf2f((unsigned short)(vbits[n].y >> 16));
    }
    // t2 row (p*5+a): segment p>>4, local (p&15)*5+a, second overlay half
    unsigned short* t2p = t2b + (size_t)(p >> 4) * SEG + 10240 + ((p & 15) * 5) * 128;
#pragma unroll
    for (int j = 0; j < 4; ++j) {
      int o = o0 + j;
      int e = o / 5, a = o - e * 5;
      t2p[a * 128 + e] = f2bf(facc[j]);
    }
  }
}

// ---------------------------------------------------------------------------
// K3: MFMA Wo + residual + LN1 + FFN + residual + LN2 + transposed store.
// Block bid reads bf16 x/t2 from d_out segment bid, writes fp32 out over the
// same segment at the end (all reads barrier-separated from the store).
// ---------------------------------------------------------------------------
__global__ __launch_bounds__(256, 2) void k_ffn_mfma(
    float* out, const unsigned short* __restrict__ Wob,
    const unsigned short* __restrict__ W1b, const float* __restrict__ b1,
    const unsigned short* __restrict__ W2b, const float* __restrict__ b2,
    const float* __restrict__ g1, const float* __restrict__ be1,
    const float* __restrict__ g2, const float* __restrict__ be2)
{
  __shared__ unsigned short SH[2 * 80 * 136];
  __shared__ float mrow[80], rrow[80];
  unsigned short* Yb = SH;
  unsigned short* Hb = SH + 80 * 136;
  const int t = threadIdx.x;
  const int w = t >> 6, l = t & 63;
  const int lc = l & 15;
  const int kg = l >> 4;
  const int c0 = (2 * w) * 16 + lc;
  const int c1 = c0 + 16;
  const unsigned short* xseg = (const unsigned short*)out + (size_t)blockIdx.x * SEG;
  const unsigned short* t2seg = xseg + 10240;

  f32x4 zac[5][2];
#pragma unroll
  for (int m = 0; m < 5; ++m)
#pragma unroll
    for (int n = 0; n < 2; ++n) zac[m][n] = (f32x4){0.f, 0.f, 0.f, 0.f};

  {
    bf8 wb[2][4];
#pragma unroll
    for (int nt = 0; nt < 2; ++nt)
#pragma unroll
      for (int kf = 0; kf < 4; ++kf)
        wb[nt][kf] = *reinterpret_cast<const bf8*>(
            &Wob[(size_t)((2 * w + nt) * 16 + lc) * DD + kf * 32 + kg * 8]);
#pragma unroll
    for (int mt = 0; mt < 5; ++mt) {
      const unsigned short* ap = t2seg + (mt * 16 + lc) * DD + kg * 8;
      bf8 a0 = *reinterpret_cast<const bf8*>(ap);
      bf8 a1 = *reinterpret_cast<const bf8*>(ap + 32);
      bf8 a2 = *reinterpret_cast<const bf8*>(ap + 64);
      bf8 a3 = *reinterpret_cast<const bf8*>(ap + 96);
#pragma unroll
      for (int nt = 0; nt < 2; ++nt) {
        zac[mt][nt] = __builtin_amdgcn_mfma_f32_16x16x32_bf16(a0, wb[nt][0], zac[mt][nt], 0, 0, 0);
        zac[mt][nt] = __builtin_amdgcn_mfma_f32_16x16x32_bf16(a1, wb[nt][1], zac[mt][nt], 0, 0, 0);
        zac[mt][nt] = __builtin_amdgcn_mfma_f32_16x16x32_bf16(a2, wb[nt][2], zac[mt][nt], 0, 0, 0);
        zac[mt][nt] = __builtin_amdgcn_mfma_f32_16x16x32_bf16(a3, wb[nt][3], zac[mt][nt], 0, 0, 0);
      }
    }
  }
#pragma unroll
  for (int mt = 0; mt < 5; ++mt) {
    int rb = mt * 16 + kg * 4;
#pragma unroll
    for (int j = 0; j < 4; ++j) {
      int row = rb + j;
      zac[mt][0][j] += bf2f(xseg[row * DD + c0]);
      zac[mt][1][j] += bf2f(xseg[row * DD + c1]);
      Yb[row * 136 + c0] = f2bf(zac[mt][0][j]);
      Yb[row * 136 + c1] = f2bf(zac[mt][1][j]);
    }
  }
  __syncthreads();
  if (t < 160) {
    int row = t >> 1, hf = t & 1;
    const unsigned short* rp = Yb + row * 136 + hf * 64;
    float s = 0.f, s2 = 0.f;
#pragma unroll
    for (int c8 = 0; c8 < 8; ++c8) {
      bf8 v8 = *reinterpret_cast<const bf8*>(rp + c8 * 8);
#pragma unroll
      for (int j = 0; j < 8; ++j) {
        float f = bf2f((unsigned short)v8[j]);
        s += f; s2 += f * f;
      }
    }
    s += __shfl_xor(s, 1); s2 += __shfl_xor(s2, 1);
    if (!hf) {
      float mm = s * (1.f / 128.f);
      float vv = s2 * (1.f / 128.f) - mm * mm;
      mrow[row] = mm;
      rrow[row] = rsqrtf(vv + 1e-5f);
    }
  }
  __syncthreads();
  {
    float g1a = g1[c0], g1b = g1[c1], e1a = be1[c0], e1b = be1[c1];
#pragma unroll
    for (int mt = 0; mt < 5; ++mt) {
      int rb = mt * 16 + kg * 4;
#pragma unroll
      for (int j = 0; j < 4; ++j) {
        int row = rb + j;
        float mm = mrow[row], rr = rrow[row];
        float y0 = (zac[mt][0][j] - mm) * rr * g1a + e1a;
        float y1 = (zac[mt][1][j] - mm) * rr * g1b + e1b;
        zac[mt][0][j] = y0; zac[mt][1][j] = y1;
        Yb[row * 136 + c0] = f2bf(y0);
        Yb[row * 136 + c1] = f2bf(y1);
      }
    }
  }
  __syncthreads();
  f32x4 oac[5][2];
#pragma unroll
  for (int m = 0; m < 5; ++m)
#pragma unroll
    for (int n = 0; n < 2; ++n) oac[m][n] = (f32x4){0.f, 0.f, 0.f, 0.f};

  for (int c = 0; c < 4; ++c) {
    bf8 w1f[2][4];
#pragma unroll
    for (int nt = 0; nt < 2; ++nt)
#pragma unroll
      for (int kf = 0; kf < 4; ++kf)
        w1f[nt][kf] = *reinterpret_cast<const bf8*>(
            &W1b[(size_t)(c * 128 + (2 * w + nt) * 16 + lc) * DD + kf * 32 + kg * 8]);
    f32x4 hac[5][2];
#pragma unroll
    for (int m = 0; m < 5; ++m)
#pragma unroll
      for (int n = 0; n < 2; ++n) hac[m][n] = (f32x4){0.f, 0.f, 0.f, 0.f};
#pragma unroll
    for (int mt = 0; mt < 5; ++mt) {
      const unsigned short* yp = Yb + (mt * 16 + lc) * 136 + kg * 8;
      bf8 a0 = *reinterpret_cast<const bf8*>(yp);
      bf8 a1 = *reinterpret_cast<const bf8*>(yp + 32);
      bf8 a2 = *reinterpret_cast<const bf8*>(yp + 64);
      bf8 a3 = *reinterpret_cast<const bf8*>(yp + 96);
#pragma unroll
      for (int nt = 0; nt < 2; ++nt) {
        hac[mt][nt] = __builtin_amdgcn_mfma_f32_16x16x32_bf16(a0, w1f[nt][0], hac[mt][nt], 0, 0, 0);
        hac[mt][nt] = __builtin_amdgcn_mfma_f32_16x16x32_bf16(a1, w1f[nt][1], hac[mt][nt], 0, 0, 0);
        hac[mt][nt] = __builtin_amdgcn_mfma_f32_16x16x32_bf16(a2, w1f[nt][2], hac[mt][nt], 0, 0, 0);
        hac[mt][nt] = __builtin_amdgcn_mfma_f32_16x16x32_bf16(a3, w1f[nt][3], hac[mt][nt], 0, 0, 0);
      }
    }
    float b1a = b1[c * 128 + c0], b1b = b1[c * 128 + c1];
    __syncthreads();
#pragma unroll
    for (int mt = 0; mt < 5; ++mt) {
      int rb = mt * 16 + kg * 4;
#pragma unroll
      for (int j = 0; j < 4; ++j) {
        int row = rb + j;
        Hb[row * 136 + c0] = f2bf(fmaxf(hac[mt][0][j] + b1a, 0.f));
        Hb[row * 136 + c1] = f2bf(fmaxf(hac[mt][1][j] + b1b, 0.f));
      }
    }
    __syncthreads();
    bf8 w2f[2][4];
#pragma unroll
    for (int nt = 0; nt < 2; ++nt)
#pragma unroll
      for (int kf = 0; kf < 4; ++kf)
        w2f[nt][kf] = *reinterpret_cast<const bf8*>(
            &W2b[(size_t)((2 * w + nt) * 16 + lc) * FF + c * 128 + kf * 32 + kg * 8]);
#pragma unroll
    for (int mt = 0; mt < 5; ++mt) {
      const unsigned short* hp = Hb + (mt * 16 + lc) * 136 + kg * 8;
      bf8 a0 = *reinterpret_cast<const bf8*>(hp);
      bf8 a1 = *reinterpret_cast<const bf8*>(hp + 32);
      bf8 a2 = *reinterpret_cast<const bf8*>(hp + 64);
      bf8 a3 = *reinterpret_cast<const bf8*>(hp + 96);
#pragma unroll
      for (int nt = 0; nt < 2; ++nt) {
        oac[mt][nt] = __builtin_amdgcn_mfma_f32_16x16x32_bf16(a0, w2f[nt][0], oac[mt][nt], 0, 0, 0);
        oac[mt][nt] = __builtin_amdgcn_mfma_f32_16x16x32_bf16(a1, w2f[nt][1], oac[mt][nt], 0, 0, 0);
        oac[mt][nt] = __builtin_amdgcn_mfma_f32_16x16x32_bf16(a2, w2f[nt][2], oac[mt][nt], 0, 0, 0);
        oac[mt][nt] = __builtin_amdgcn_mfma_f32_16x16x32_bf16(a3, w2f[nt][3], oac[mt][nt], 0, 0, 0);
      }
    }
  }
  __syncthreads();
  {
    float b2a = b2[c0], b2b = b2[c1];
#pragma unroll
    for (int mt = 0; mt < 5; ++mt) {
      int rb = mt * 16 + kg * 4;
#pragma unroll
      for (int j = 0; j < 4; ++j) {
        int row = rb + j;
        float v0 = zac[mt][0][j] + oac[mt][0][j] + b2a;
        float v1 = zac[mt][1][j] + oac[mt][1][j] + b2b;
        oac[mt][0][j] = v0; oac[mt][1][j] = v1;
        Yb[row * 136 + c0] = f2bf(v0);
        Yb[row * 136 + c1] = f2bf(v1);
      }
    }
  }
  __syncthreads();
  if (t < 160) {
    int row = t >> 1, hf = t & 1;
    const unsigned short* rp = Yb + row * 136 + hf * 64;
    float s = 0.f, s2 = 0.f;
#pragma unroll
    for (int c8 = 0; c8 < 8; ++c8) {
      bf8 v8 = *reinterpret_cast<const bf8*>(rp + c8 * 8);
#pragma unroll
      for (int j = 0; j < 8; ++j) {
        float f = bf2f((unsigned short)v8[j]);
        s += f; s2 += f * f;
      }
    }
    s += __shfl_xor(s, 1); s2 += __shfl_xor(s2, 1);
    if (!hf) {
      float mm = s * (1.f / 128.f);
      float vv = s2 * (1.f / 128.f) - mm * mm;
      mrow[row] = mm;
      rrow[row] = rsqrtf(vv + 1e-5f);
    }
  }
  __syncthreads();
  {
    float* fb = (float*)SH;
    float g2a = g2[c0], g2b = g2[c1], e2a = be2[c0], e2b = be2[c1];
#pragma unroll
    for (int mt = 0; mt < 5; ++mt) {
      int rb = mt * 16 + kg * 4;
#pragma unroll
      for (int j = 0; j < 4; ++j) {
        int row = rb + j;
        float mm = mrow[row], rr = rrow[row];
        fb[row * 132 + c0] = (oac[mt][0][j] - mm) * rr * g2a + e2a;
        fb[row * 132 + c1] = (oac[mt][1][j] - mm) * rr * g2b + e2b;
      }
    }
    __syncthreads();   // all overlay reads complete before out overwrites segment
    const size_t ob = (size_t)blockIdx.x * 16 * PD;
    for (int i = t; i < 10240; i += 256) {
      int pl = i / PD, rem = i - pl * PD;
      int d = rem / 5, a = rem - d * 5;
      out[ob + i] = fb[(pl * 5 + a) * 132 + d];
    }
  }
}

// ---------------------------------------------------------------------------
extern "C" void kernel_launch(void* const* d_in, const int* in_sizes, int n_in,
                              void* d_out, int out_size, void* d_ws, size_t ws_size,
                              hipStream_t stream) {
  (void)in_sizes; (void)n_in; (void)out_size; (void)ws_size;
  const float* tgt  = (const float*)d_in[0];
  const int*   idx  = (const int*)d_in[1];
  const float* dist = (const float*)d_in[3];
  const float* Wq   = (const float*)d_in[4];
  const float* Wk   = (const float*)d_in[5];
  const float* Wo   = (const float*)d_in[6];
  const float* W1   = (const float*)d_in[7];
  const float* b1f  = (const float*)d_in[8];
  const float* W2   = (const float*)d_in[9];
  const float* b2f  = (const float*)d_in[10];
  const float* g1   = (const float*)d_in[11];
  const float* be1  = (const float*)d_in[12];
  const float* g2   = (const float*)d_in[13];
  const float* be2  = (const float*)d_in[14];
  float* out = (float*)d_out;

  // ws (shorts): kqb [P][1280] | Wob | W1b | W2b | Wqb | Wkb  = 51.56 MB total
  unsigned short* kqb = (unsigned short*)d_ws;
  unsigned short* Wob = kqb + (size_t)PP * 1280;
  unsigned short* W1b = Wob + DD * DD;
  unsigned short* W2b = W1b + FF * DD;
  unsigned short* Wqb = W2b + FF * DD;
  unsigned short* Wkb = Wqb + DD * DD;
  unsigned short* ovl = (unsigned short*)d_out;   // segment overlay (x | t2)

  k_wconv  <<<256, 256, 0, stream>>>(Wo, W1, W2, Wq, Wk, Wob, W1b, W2b, Wqb, Wkb);
  k_xpose  <<<PP / 8, 320, 0, stream>>>(tgt, ovl);
  k_qk_gemm<<<ROWS / 80, 256, 0, stream>>>(ovl, Wqb, Wkb, kqb);
  k_attn   <<<PP, 256, 0, stream>>>(kqb, idx, dist, ovl);
  k_ffn_mfma<<<ROWS / 80, 256, 0, stream>>>(out, Wob, W1b, b1f, W2b, b2f,
                                            g1, be1, g2, be2);
}

// Round 8
// 316.636 us; speedup vs baseline: 1.1288x; 1.1288x over previous
//
#include <hip/hip_runtime.h>

#define PP   20000
#define NN   16
#define DD   128
#define HH   8
#define ANC  5
#define FF   512
#define PD   640
#define ROWS (PP * ANC)          // 100000 rows of [128]
#define SEG  20480               // shorts per d_out segment (80 rows x 128 x 2 halves)

// d_out overlay (per 80-row segment s, byte base s*40960):
//   [0,20480)B  : bf16 x rows   (row r -> s=r/80, local=r%80, +local*256B)
//   [20480,40960)B : bf16 t2 rows (same row mapping)
// k_ffn block s reads exactly segment s and finally overwrites it with fp32 out.

typedef __attribute__((ext_vector_type(8))) short  bf8;     // 8 bf16 (4 VGPRs)
typedef __attribute__((ext_vector_type(8))) unsigned short ushort8;
typedef __attribute__((ext_vector_type(4))) unsigned short us4;
typedef __attribute__((ext_vector_type(4))) float  f32x4;

__device__ inline float bf2f(unsigned short u) {
  union { unsigned int i; float f; } v; v.i = ((unsigned int)u) << 16; return v.f;
}
__device__ inline unsigned short f2bf(float f) {
  union { float f; unsigned int i; } v; v.f = f;
  unsigned int r = v.i + 0x7FFFu + ((v.i >> 16) & 1u);
  return (unsigned short)(r >> 16);
}

// ---------------------------------------------------------------------------
// K0: weight conversion fp32 -> bf16 (once per launch)
// ---------------------------------------------------------------------------
__global__ void k_wconv(const float* __restrict__ Wo, const float* __restrict__ W1,
                        const float* __restrict__ W2, const float* __restrict__ Wq,
                        const float* __restrict__ Wk,
                        unsigned short* __restrict__ Wob, unsigned short* __restrict__ W1b,
                        unsigned short* __restrict__ W2b, unsigned short* __restrict__ Wqb,
                        unsigned short* __restrict__ Wkb)
{
  int i = blockIdx.x * 256 + threadIdx.x;
  if (i < 16384) { Wob[i] = f2bf(Wo[i]); Wqb[i] = f2bf(Wq[i]); Wkb[i] = f2bf(Wk[i]); }
  if (i < 65536) { W1b[i] = f2bf(W1[i]); W2b[i] = f2bf(W2[i]); }
}

// ---------------------------------------------------------------------------
// K1a: transpose tgt [p][e*5+a] -> bf16 x rows [p*5+a][e] into d_out overlay.
// ---------------------------------------------------------------------------
__global__ __launch_bounds__(320) void k_xpose(
    const float* __restrict__ tgt, unsigned short* __restrict__ xb)
{
  __shared__ float xs[5 * 1032];
  const int t = threadIdx.x;
  const int p0 = blockIdx.x * 8;
  const float* src = tgt + (size_t)p0 * PD;
#pragma unroll
  for (int i = 0; i < 16; ++i) {
    int lin = t + i * 320;
    float v = src[lin];
    int pt = lin / PD;
    int rem = lin - pt * PD;
    int e = rem / 5;
    int a = rem - e * 5;
    xs[a * 1032 + e * 8 + pt] = v;
  }
  __syncthreads();
  // 40 rows per block; rows r0..r0+39 live in segment r0/80, half (blockIdx&1)
  const size_t base = (size_t)(blockIdx.x >> 1) * SEG + (size_t)(blockIdx.x & 1) * 5120;
  for (int i = t; i < 5120; i += 320) {
    int row_l = i >> 7, col = i & 127;
    int pt = row_l / 5, a = row_l - pt * 5;
    xb[base + i] = f2bf(xs[a * 1032 + col * 8 + pt]);
  }
}

// ---------------------------------------------------------------------------
// K1b: MFMA GEMM q = x@Wq^T, k = x@Wk^T. Outputs:
//   kq8[p][0..640)B   = K row fp8 e4m3 (layout e*5+a)
//   kq8[p][640..1280)B = V row fp8 (= q, layout e*5+a)
//   qb16[p][640]       = q row bf16 (self-query for the dot)
// ---------------------------------------------------------------------------
__global__ __launch_bounds__(256) void k_qk_gemm(
    const unsigned short* __restrict__ xb, const unsigned short* __restrict__ Wqb,
    const unsigned short* __restrict__ Wkb, unsigned char* __restrict__ kq8,
    unsigned short* __restrict__ qb16)
{
  __shared__ unsigned short Sb[80 * 136];
  const int t = threadIdx.x;
  const int w = t >> 6, l = t & 63;
  const int lc = l & 15, kg = l >> 4;
  const int p0 = blockIdx.x * 16;
  const unsigned short* xseg = xb + (size_t)blockIdx.x * SEG;  // 80 rows x 128

  f32x4 zq[5][2], zk[5][2];
#pragma unroll
  for (int m = 0; m < 5; ++m)
#pragma unroll
    for (int n = 0; n < 2; ++n) {
      zq[m][n] = (f32x4){0.f, 0.f, 0.f, 0.f};
      zk[m][n] = (f32x4){0.f, 0.f, 0.f, 0.f};
    }
  bf8 wq[2][4], wk[2][4];
#pragma unroll
  for (int nt = 0; nt < 2; ++nt)
#pragma unroll
    for (int kf = 0; kf < 4; ++kf) {
      size_t wo = (size_t)((2 * w + nt) * 16 + lc) * DD + kf * 32 + kg * 8;
      wq[nt][kf] = *reinterpret_cast<const bf8*>(&Wqb[wo]);
      wk[nt][kf] = *reinterpret_cast<const bf8*>(&Wkb[wo]);
    }
#pragma unroll
  for (int mt = 0; mt < 5; ++mt) {
    const unsigned short* ap = xseg + (mt * 16 + lc) * DD + kg * 8;
    bf8 a0 = *reinterpret_cast<const bf8*>(ap);
    bf8 a1 = *reinterpret_cast<const bf8*>(ap + 32);
    bf8 a2 = *reinterpret_cast<const bf8*>(ap + 64);
    bf8 a3 = *reinterpret_cast<const bf8*>(ap + 96);
#pragma unroll
    for (int nt = 0; nt < 2; ++nt) {
      zq[mt][nt] = __builtin_amdgcn_mfma_f32_16x16x32_bf16(a0, wq[nt][0], zq[mt][nt], 0, 0, 0);
      zq[mt][nt] = __builtin_amdgcn_mfma_f32_16x16x32_bf16(a1, wq[nt][1], zq[mt][nt], 0, 0, 0);
      zq[mt][nt] = __builtin_amdgcn_mfma_f32_16x16x32_bf16(a2, wq[nt][2], zq[mt][nt], 0, 0, 0);
      zq[mt][nt] = __builtin_amdgcn_mfma_f32_16x16x32_bf16(a3, wq[nt][3], zq[mt][nt], 0, 0, 0);
      zk[mt][nt] = __builtin_amdgcn_mfma_f32_16x16x32_bf16(a0, wk[nt][0], zk[mt][nt], 0, 0, 0);
      zk[mt][nt] = __builtin_amdgcn_mfma_f32_16x16x32_bf16(a1, wk[nt][1], zk[mt][nt], 0, 0, 0);
      zk[mt][nt] = __builtin_amdgcn_mfma_f32_16x16x32_bf16(a2, wk[nt][2], zk[mt][nt], 0, 0, 0);
      zk[mt][nt] = __builtin_amdgcn_mfma_f32_16x16x32_bf16(a3, wk[nt][3], zk[mt][nt], 0, 0, 0);
    }
  }
  // ---- epilogue: Q half -> qb16 (bf16) + V fp8; then K half -> fp8 ----
#pragma unroll
  for (int mt = 0; mt < 5; ++mt)
#pragma unroll
    for (int j = 0; j < 4; ++j)
#pragma unroll
      for (int nt = 0; nt < 2; ++nt)
        Sb[(mt * 16 + kg * 4 + j) * 136 + (2 * w + nt) * 16 + lc] = f2bf(zq[mt][nt][j]);
  __syncthreads();
  for (int i = t * 4; i < 10240; i += 1024) {
    int pl = i / 640, rem = i - pl * 640;
    unsigned short u[4]; float f[4];
#pragma unroll
    for (int j = 0; j < 4; ++j) {
      int o = rem + j; int d = o / 5, a = o - d * 5;
      u[j] = Sb[(pl * 5 + a) * 136 + d];
      f[j] = bf2f(u[j]);
    }
    us4 uv = {u[0], u[1], u[2], u[3]};
    *reinterpret_cast<us4*>(&qb16[(size_t)(p0 + pl) * 640 + rem]) = uv;
    int wd = 0;
    wd = __builtin_amdgcn_cvt_pk_fp8_f32(f[0], f[1], wd, false);
    wd = __builtin_amdgcn_cvt_pk_fp8_f32(f[2], f[3], wd, true);
    *reinterpret_cast<int*>(&kq8[(size_t)(p0 + pl) * 1280 + 640 + rem]) = wd;
  }
  __syncthreads();
#pragma unroll
  for (int mt = 0; mt < 5; ++mt)
#pragma unroll
    for (int j = 0; j < 4; ++j)
#pragma unroll
      for (int nt = 0; nt < 2; ++nt)
        Sb[(mt * 16 + kg * 4 + j) * 136 + (2 * w + nt) * 16 + lc] = f2bf(zk[mt][nt][j]);
  __syncthreads();
  for (int i = t * 4; i < 10240; i += 1024) {
    int pl = i / 640, rem = i - pl * 640;
    float f[4];
#pragma unroll
    for (int j = 0; j < 4; ++j) {
      int o = rem + j; int d = o / 5, a = o - d * 5;
      f[j] = bf2f(Sb[(pl * 5 + a) * 136 + d]);
    }
    int wd = 0;
    wd = __builtin_amdgcn_cvt_pk_fp8_f32(f[0], f[1], wd, false);
    wd = __builtin_amdgcn_cvt_pk_fp8_f32(f[2], f[3], wd, true);
    *reinterpret_cast<int*>(&kq8[(size_t)(p0 + pl) * 1280 + rem]) = wd;
  }
}

// ---------------------------------------------------------------------------
// K2: attention. One point per block. K fp8 read DIRECTLY from global
// (zero cross-thread reuse -> no LDS staging); q bf16 broadcast from LDS;
// V fp8 in 16 VGPRs. LDS ~2.4 KB -> high occupancy.
// ---------------------------------------------------------------------------
__global__ __launch_bounds__(256, 6) void k_attn(
    const unsigned char* __restrict__ kq8, const unsigned short* __restrict__ qb16,
    const int* __restrict__ idx, const float* __restrict__ dist,
    unsigned short* __restrict__ t2b)
{
  __shared__ unsigned short qsh[640];
  __shared__ float sc[128];
  __shared__ float att[128];
  __shared__ int sidx[NN];
  const int t = threadIdx.x;
  const int p = blockIdx.x;
  if (t < NN) sidx[t] = idx[p * NN + t];
  if (t < 80)
    *reinterpret_cast<ushort8*>(&qsh[t * 8]) =
        *reinterpret_cast<const ushort8*>(&qb16[(size_t)p * 640 + t * 8]);
  float dv = 0.f;
  if (t < 128) dv = dist[(size_t)p * 128 + (t & 15) * 8 + (t >> 4)];
  __syncthreads();
  // V fp8 preload into registers (1 dword per neighbor)
  unsigned vbits[16];
  const int o0 = (t < 160) ? t * 4 : 0;   // element (=byte) offset in V half
  if (t < 160) {
#pragma unroll
    for (int n = 0; n < 16; ++n)
      vbits[n] = *reinterpret_cast<const unsigned*>(
          &kq8[(size_t)sidx[n] * 1280 + 640 + o0]);
  }
  // dot: K fp8 direct from global, q bf16 broadcast from LDS
  if (t < 128) {
    int n = t & 15, h = t >> 4;
    const unsigned char* kp = &kq8[(size_t)sidx[n] * 1280 + h * 80];
    const unsigned short* qp = &qsh[h * 80];
    float acc = 0.f;
#pragma unroll
    for (int j4 = 0; j4 < 5; ++j4) {
      uint4 kw = *reinterpret_cast<const uint4*>(kp + j4 * 16);
      ushort8 qa = *reinterpret_cast<const ushort8*>(qp + j4 * 16);
      ushort8 qb = *reinterpret_cast<const ushort8*>(qp + j4 * 16 + 8);
      acc += __builtin_amdgcn_cvt_f32_fp8(kw.x, 0) * bf2f(qa[0]);
      acc += __builtin_amdgcn_cvt_f32_fp8(kw.x, 1) * bf2f(qa[1]);
      acc += __builtin_amdgcn_cvt_f32_fp8(kw.x, 2) * bf2f(qa[2]);
      acc += __builtin_amdgcn_cvt_f32_fp8(kw.x, 3) * bf2f(qa[3]);
      acc += __builtin_amdgcn_cvt_f32_fp8(kw.y, 0) * bf2f(qa[4]);
      acc += __builtin_amdgcn_cvt_f32_fp8(kw.y, 1) * bf2f(qa[5]);
      acc += __builtin_amdgcn_cvt_f32_fp8(kw.y, 2) * bf2f(qa[6]);
      acc += __builtin_amdgcn_cvt_f32_fp8(kw.y, 3) * bf2f(qa[7]);
      acc += __builtin_amdgcn_cvt_f32_fp8(kw.z, 0) * bf2f(qb[0]);
      acc += __builtin_amdgcn_cvt_f32_fp8(kw.z, 1) * bf2f(qb[1]);
      acc += __builtin_amdgcn_cvt_f32_fp8(kw.z, 2) * bf2f(qb[2]);
      acc += __builtin_amdgcn_cvt_f32_fp8(kw.z, 3) * bf2f(qb[3]);
      acc += __builtin_amdgcn_cvt_f32_fp8(kw.w, 0) * bf2f(qb[4]);
      acc += __builtin_amdgcn_cvt_f32_fp8(kw.w, 1) * bf2f(qb[5]);
      acc += __builtin_amdgcn_cvt_f32_fp8(kw.w, 2) * bf2f(qb[6]);
      acc += __builtin_amdgcn_cvt_f32_fp8(kw.w, 3) * bf2f(qb[7]);
    }
    sc[h * 16 + n] = (acc + dv) * 0.25f;
  }
  __syncthreads();
  if (t < 8) {
    float m = -1e30f;
#pragma unroll
    for (int n = 0; n < 16; ++n) m = fmaxf(m, sc[t * 16 + n]);
    float s = 0.f;
    float ev[16];
#pragma unroll
    for (int n = 0; n < 16; ++n) { ev[n] = __expf(sc[t * 16 + n] - m); s += ev[n]; }
    float inv = 1.f / s;
#pragma unroll
    for (int n = 0; n < 16; ++n) att[t * 16 + n] = ev[n] * inv;
  }
  __syncthreads();
  if (t < 160) {
    const int h = o0 / 80;     // 4-elem chunk never straddles a head (4 | 80)
    float facc[4] = {0.f, 0.f, 0.f, 0.f};
#pragma unroll
    for (int n = 0; n < 16; ++n) {
      float aw = att[h * 16 + n];
      facc[0] += aw * __builtin_amdgcn_cvt_f32_fp8(vbits[n], 0);
      facc[1] += aw * __builtin_amdgcn_cvt_f32_fp8(vbits[n], 1);
      facc[2] += aw * __builtin_amdgcn_cvt_f32_fp8(vbits[n], 2);
      facc[3] += aw * __builtin_amdgcn_cvt_f32_fp8(vbits[n], 3);
    }
    // t2 row (p*5+a): segment p>>4, local (p&15)*5+a, second overlay half
    unsigned short* t2p = t2b + (size_t)(p >> 4) * SEG + 10240 + ((p & 15) * 5) * 128;
#pragma unroll
    for (int j = 0; j < 4; ++j) {
      int o = o0 + j;
      int e = o / 5, a = o - e * 5;
      t2p[a * 128 + e] = f2bf(facc[j]);
    }
  }
}

// ---------------------------------------------------------------------------
// K3: MFMA Wo + residual + LN1 + FFN + residual + LN2 + transposed store.
// Block bid reads bf16 x/t2 from d_out segment bid, writes fp32 out over the
// same segment at the end (all reads barrier-separated from the store).
// ---------------------------------------------------------------------------
__global__ __launch_bounds__(256, 2) void k_ffn_mfma(
    float* out, const unsigned short* __restrict__ Wob,
    const unsigned short* __restrict__ W1b, const float* __restrict__ b1,
    const unsigned short* __restrict__ W2b, const float* __restrict__ b2,
    const float* __restrict__ g1, const float* __restrict__ be1,
    const float* __restrict__ g2, const float* __restrict__ be2)
{
  __shared__ unsigned short SH[2 * 80 * 136];
  __shared__ float mrow[80], rrow[80];
  unsigned short* Yb = SH;
  unsigned short* Hb = SH + 80 * 136;
  const int t = threadIdx.x;
  const int w = t >> 6, l = t & 63;
  const int lc = l & 15;
  const int kg = l >> 4;
  const int c0 = (2 * w) * 16 + lc;
  const int c1 = c0 + 16;
  const unsigned short* xseg = (const unsigned short*)out + (size_t)blockIdx.x * SEG;
  const unsigned short* t2seg = xseg + 10240;

  f32x4 zac[5][2];
#pragma unroll
  for (int m = 0; m < 5; ++m)
#pragma unroll
    for (int n = 0; n < 2; ++n) zac[m][n] = (f32x4){0.f, 0.f, 0.f, 0.f};

  {
    bf8 wb[2][4];
#pragma unroll
    for (int nt = 0; nt < 2; ++nt)
#pragma unroll
      for (int kf = 0; kf < 4; ++kf)
        wb[nt][kf] = *reinterpret_cast<const bf8*>(
            &Wob[(size_t)((2 * w + nt) * 16 + lc) * DD + kf * 32 + kg * 8]);
#pragma unroll
    for (int mt = 0; mt < 5; ++mt) {
      const unsigned short* ap = t2seg + (mt * 16 + lc) * DD + kg * 8;
      bf8 a0 = *reinterpret_cast<const bf8*>(ap);
      bf8 a1 = *reinterpret_cast<const bf8*>(ap + 32);
      bf8 a2 = *reinterpret_cast<const bf8*>(ap + 64);
      bf8 a3 = *reinterpret_cast<const bf8*>(ap + 96);
#pragma unroll
      for (int nt = 0; nt < 2; ++nt) {
        zac[mt][nt] = __builtin_amdgcn_mfma_f32_16x16x32_bf16(a0, wb[nt][0], zac[mt][nt], 0, 0, 0);
        zac[mt][nt] = __builtin_amdgcn_mfma_f32_16x16x32_bf16(a1, wb[nt][1], zac[mt][nt], 0, 0, 0);
        zac[mt][nt] = __builtin_amdgcn_mfma_f32_16x16x32_bf16(a2, wb[nt][2], zac[mt][nt], 0, 0, 0);
        zac[mt][nt] = __builtin_amdgcn_mfma_f32_16x16x32_bf16(a3, wb[nt][3], zac[mt][nt], 0, 0, 0);
      }
    }
  }
#pragma unroll
  for (int mt = 0; mt < 5; ++mt) {
    int rb = mt * 16 + kg * 4;
#pragma unroll
    for (int j = 0; j < 4; ++j) {
      int row = rb + j;
      zac[mt][0][j] += bf2f(xseg[row * DD + c0]);
      zac[mt][1][j] += bf2f(xseg[row * DD + c1]);
      Yb[row * 136 + c0] = f2bf(zac[mt][0][j]);
      Yb[row * 136 + c1] = f2bf(zac[mt][1][j]);
    }
  }
  __syncthreads();
  if (t < 160) {
    int row = t >> 1, hf = t & 1;
    const unsigned short* rp = Yb + row * 136 + hf * 64;
    float s = 0.f, s2 = 0.f;
#pragma unroll
    for (int c8 = 0; c8 < 8; ++c8) {
      bf8 v8 = *reinterpret_cast<const bf8*>(rp + c8 * 8);
#pragma unroll
      for (int j = 0; j < 8; ++j) {
        float f = bf2f((unsigned short)v8[j]);
        s += f; s2 += f * f;
      }
    }
    s += __shfl_xor(s, 1); s2 += __shfl_xor(s2, 1);
    if (!hf) {
      float mm = s * (1.f / 128.f);
      float vv = s2 * (1.f / 128.f) - mm * mm;
      mrow[row] = mm;
      rrow[row] = rsqrtf(vv + 1e-5f);
    }
  }
  __syncthreads();
  {
    float g1a = g1[c0], g1b = g1[c1], e1a = be1[c0], e1b = be1[c1];
#pragma unroll
    for (int mt = 0; mt < 5; ++mt) {
      int rb = mt * 16 + kg * 4;
#pragma unroll
      for (int j = 0; j < 4; ++j) {
        int row = rb + j;
        float mm = mrow[row], rr = rrow[row];
        float y0 = (zac[mt][0][j] - mm) * rr * g1a + e1a;
        float y1 = (zac[mt][1][j] - mm) * rr * g1b + e1b;
        zac[mt][0][j] = y0; zac[mt][1][j] = y1;
        Yb[row * 136 + c0] = f2bf(y0);
        Yb[row * 136 + c1] = f2bf(y1);
      }
    }
  }
  __syncthreads();
  f32x4 oac[5][2];
#pragma unroll
  for (int m = 0; m < 5; ++m)
#pragma unroll
    for (int n = 0; n < 2; ++n) oac[m][n] = (f32x4){0.f, 0.f, 0.f, 0.f};

  for (int c = 0; c < 4; ++c) {
    bf8 w1f[2][4];
#pragma unroll
    for (int nt = 0; nt < 2; ++nt)
#pragma unroll
      for (int kf = 0; kf < 4; ++kf)
        w1f[nt][kf] = *reinterpret_cast<const bf8*>(
            &W1b[(size_t)(c * 128 + (2 * w + nt) * 16 + lc) * DD + kf * 32 + kg * 8]);
    f32x4 hac[5][2];
#pragma unroll
    for (int m = 0; m < 5; ++m)
#pragma unroll
      for (int n = 0; n < 2; ++n) hac[m][n] = (f32x4){0.f, 0.f, 0.f, 0.f};
#pragma unroll
    for (int mt = 0; mt < 5; ++mt) {
      const unsigned short* yp = Yb + (mt * 16 + lc) * 136 + kg * 8;
      bf8 a0 = *reinterpret_cast<const bf8*>(yp);
      bf8 a1 = *reinterpret_cast<const bf8*>(yp + 32);
      bf8 a2 = *reinterpret_cast<const bf8*>(yp + 64);
      bf8 a3 = *reinterpret_cast<const bf8*>(yp + 96);
#pragma unroll
      for (int nt = 0; nt < 2; ++nt) {
        hac[mt][nt] = __builtin_amdgcn_mfma_f32_16x16x32_bf16(a0, w1f[nt][0], hac[mt][nt], 0, 0, 0);
        hac[mt][nt] = __builtin_amdgcn_mfma_f32_16x16x32_bf16(a1, w1f[nt][1], hac[mt][nt], 0, 0, 0);
        hac[mt][nt] = __builtin_amdgcn_mfma_f32_16x16x32_bf16(a2, w1f[nt][2], hac[mt][nt], 0, 0, 0);
        hac[mt][nt] = __builtin_amdgcn_mfma_f32_16x16x32_bf16(a3, w1f[nt][3], hac[mt][nt], 0, 0, 0);
      }
    }
    float b1a = b1[c * 128 + c0], b1b = b1[c * 128 + c1];
    __syncthreads();
#pragma unroll
    for (int mt = 0; mt < 5; ++mt) {
      int rb = mt * 16 + kg * 4;
#pragma unroll
      for (int j = 0; j < 4; ++j) {
        int row = rb + j;
        Hb[row * 136 + c0] = f2bf(fmaxf(hac[mt][0][j] + b1a, 0.f));
        Hb[row * 136 + c1] = f2bf(fmaxf(hac[mt][1][j] + b1b, 0.f));
      }
    }
    __syncthreads();
    bf8 w2f[2][4];
#pragma unroll
    for (int nt = 0; nt < 2; ++nt)
#pragma unroll
      for (int kf = 0; kf < 4; ++kf)
        w2f[nt][kf] = *reinterpret_cast<const bf8*>(
            &W2b[(size_t)((2 * w + nt) * 16 + lc) * FF + c * 128 + kf * 32 + kg * 8]);
#pragma unroll
    for (int mt = 0; mt < 5; ++mt) {
      const unsigned short* hp = Hb + (mt * 16 + lc) * 136 + kg * 8;
      bf8 a0 = *reinterpret_cast<const bf8*>(hp);
      bf8 a1 = *reinterpret_cast<const bf8*>(hp + 32);
      bf8 a2 = *reinterpret_cast<const bf8*>(hp + 64);
      bf8 a3 = *reinterpret_cast<const bf8*>(hp + 96);
#pragma unroll
      for (int nt = 0; nt < 2; ++nt) {
        oac[mt][nt] = __builtin_amdgcn_mfma_f32_16x16x32_bf16(a0, w2f[nt][0], oac[mt][nt], 0, 0, 0);
        oac[mt][nt] = __builtin_amdgcn_mfma_f32_16x16x32_bf16(a1, w2f[nt][1], oac[mt][nt], 0, 0, 0);
        oac[mt][nt] = __builtin_amdgcn_mfma_f32_16x16x32_bf16(a2, w2f[nt][2], oac[mt][nt], 0, 0, 0);
        oac[mt][nt] = __builtin_amdgcn_mfma_f32_16x16x32_bf16(a3, w2f[nt][3], oac[mt][nt], 0, 0, 0);
      }
    }
  }
  __syncthreads();
  {
    float b2a = b2[c0], b2b = b2[c1];
#pragma unroll
    for (int mt = 0; mt < 5; ++mt) {
      int rb = mt * 16 + kg * 4;
#pragma unroll
      for (int j = 0; j < 4; ++j) {
        int row = rb + j;
        float v0 = zac[mt][0][j] + oac[mt][0][j] + b2a;
        float v1 = zac[mt][1][j] + oac[mt][1][j] + b2b;
        oac[mt][0][j] = v0; oac[mt][1][j] = v1;
        Yb[row * 136 + c0] = f2bf(v0);
        Yb[row * 136 + c1] = f2bf(v1);
      }
    }
  }
  __syncthreads();
  if (t < 160) {
    int row = t >> 1, hf = t & 1;
    const unsigned short* rp = Yb + row * 136 + hf * 64;
    float s = 0.f, s2 = 0.f;
#pragma unroll
    for (int c8 = 0; c8 < 8; ++c8) {
      bf8 v8 = *reinterpret_cast<const bf8*>(rp + c8 * 8);
#pragma unroll
      for (int j = 0; j < 8; ++j) {
        float f = bf2f((unsigned short)v8[j]);
        s += f; s2 += f * f;
      }
    }
    s += __shfl_xor(s, 1); s2 += __shfl_xor(s2, 1);
    if (!hf) {
      float mm = s * (1.f / 128.f);
      float vv = s2 * (1.f / 128.f) - mm * mm;
      mrow[row] = mm;
      rrow[row] = rsqrtf(vv + 1e-5f);
    }
  }
  __syncthreads();
  {
    float* fb = (float*)SH;
    float g2a = g2[c0], g2b = g2[c1], e2a = be2[c0], e2b = be2[c1];
#pragma unroll
    for (int mt = 0; mt < 5; ++mt) {
      int rb = mt * 16 + kg * 4;
#pragma unroll
      for (int j = 0; j < 4; ++j) {
        int row = rb + j;
        float mm = mrow[row], rr = rrow[row];
        fb[row * 132 + c0] = (oac[mt][0][j] - mm) * rr * g2a + e2a;
        fb[row * 132 + c1] = (oac[mt][1][j] - mm) * rr * g2b + e2b;
      }
    }
    __syncthreads();   // all overlay reads complete before out overwrites segment
    const size_t ob = (size_t)blockIdx.x * 16 * PD;
    for (int i = t; i < 10240; i += 256) {
      int pl = i / PD, rem = i - pl * PD;
      int d = rem / 5, a = rem - d * 5;
      out[ob + i] = fb[(pl * 5 + a) * 132 + d];
    }
  }
}

// ---------------------------------------------------------------------------
extern "C" void kernel_launch(void* const* d_in, const int* in_sizes, int n_in,
                              void* d_out, int out_size, void* d_ws, size_t ws_size,
                              hipStream_t stream) {
  (void)in_sizes; (void)n_in; (void)out_size; (void)ws_size;
  const float* tgt  = (const float*)d_in[0];
  const int*   idx  = (const int*)d_in[1];
  const float* dist = (const float*)d_in[3];
  const float* Wq   = (const float*)d_in[4];
  const float* Wk   = (const float*)d_in[5];
  const float* Wo   = (const float*)d_in[6];
  const float* W1   = (const float*)d_in[7];
  const float* b1f  = (const float*)d_in[8];
  const float* W2   = (const float*)d_in[9];
  const float* b2f  = (const float*)d_in[10];
  const float* g1   = (const float*)d_in[11];
  const float* be1  = (const float*)d_in[12];
  const float* g2   = (const float*)d_in[13];
  const float* be2  = (const float*)d_in[14];
  float* out = (float*)d_out;

  // ws: kq8 (fp8, 25.6 MB) | qb16 (bf16, 25.6 MB) | bf16 weights (0.36 MB)
  unsigned char*  kq8  = (unsigned char*)d_ws;
  unsigned short* qb16 = (unsigned short*)(kq8 + (size_t)PP * 1280);
  unsigned short* Wob  = qb16 + (size_t)PP * 640;
  unsigned short* W1b  = Wob + DD * DD;
  unsigned short* W2b  = W1b + FF * DD;
  unsigned short* Wqb  = W2b + FF * DD;
  unsigned short* Wkb  = Wqb + DD * DD;
  unsigned short* ovl  = (unsigned short*)d_out;   // segment overlay (x | t2)

  k_wconv  <<<256, 256, 0, stream>>>(Wo, W1, W2, Wq, Wk, Wob, W1b, W2b, Wqb, Wkb);
  k_xpose  <<<PP / 8, 320, 0, stream>>>(tgt, ovl);
  k_qk_gemm<<<ROWS / 80, 256, 0, stream>>>(ovl, Wqb, Wkb, kq8, qb16);
  k_attn   <<<PP, 256, 0, stream>>>(kq8, qb16, idx, dist, ovl);
  k_ffn_mfma<<<ROWS / 80, 256, 0, stream>>>(out, Wob, W1b, b1f, W2b, b2f,
                                            g1, be1, g2, be2);
}